// Round 1
// baseline (1055.851 us; speedup 1.0000x reference)
//
#include <hip/hip_runtime.h>
#include <hip/hip_bf16.h>
#include <math.h>

#define B_   128
#define S_   1024
#define EMB_ 128
#define HID_ 128
#define NL_  9
#define NPOS (B_ * S_)          // 131072
#define NBLK_HEAD (NPOS / 128)  // 1024

// ---------------------------------------------------------------------------
// K1: xw[pos][j] = sum_e emb[ids[pos]][e] * W_h[e][j] + b_h[j]
// 1024 blocks x 128 threads; thread j holds Wx column j in registers.
// ---------------------------------------------------------------------------
__global__ __launch_bounds__(128, 2) void xw_kernel(
    const int* __restrict__ ids,
    const float* __restrict__ emb,
    const float* __restrict__ W_h,
    const float* __restrict__ b_h,
    float* __restrict__ xw)
{
    const int j = threadIdx.x;
    float w[EMB_];
#pragma unroll
    for (int e = 0; e < EMB_; ++e) w[e] = W_h[e * HID_ + j];
    const float bj = b_h[j];

    __shared__ float rows[8][EMB_];
    const int base = blockIdx.x * 128;

    for (int p0 = 0; p0 < 128; p0 += 8) {
        __syncthreads();
#pragma unroll
        for (int r = 0; r < 8; ++r) {
            const int pos = base + p0 + r;
            rows[r][j] = emb[(size_t)ids[pos] * EMB_ + j];
        }
        __syncthreads();
#pragma unroll
        for (int r = 0; r < 8; ++r) {
            const int pos = base + p0 + r;
            const float4* h4 = (const float4*)rows[r];
            float a0 = bj, a1 = 0.f, a2 = 0.f, a3 = 0.f;
#pragma unroll
            for (int q = 0; q < EMB_ / 4; ++q) {
                float4 u = h4[q];
                a0 += u.x * w[4 * q + 0];
                a1 += u.y * w[4 * q + 1];
                a2 += u.z * w[4 * q + 2];
                a3 += u.w * w[4 * q + 3];
            }
            xw[(size_t)pos * HID_ + j] = (a0 + a1) + (a2 + a3);
        }
    }
}

// ---------------------------------------------------------------------------
// K2: sequential recurrence. One block per batch element (128 blocks).
// Thread j holds Wh column j (128 VGPRs). h double-buffered in LDS,
// one barrier per step. Writes hs in-place over xw.
// ---------------------------------------------------------------------------
__global__ __launch_bounds__(128, 1) void rnn_kernel(
    const float* __restrict__ W_h,
    float* __restrict__ xw)   // in: xw, out: hidden states (in-place)
{
    const int b = blockIdx.x;
    const int j = threadIdx.x;

    float w[HID_];
#pragma unroll
    for (int k = 0; k < HID_; ++k) w[k] = W_h[(EMB_ + k) * HID_ + j];

    __shared__ float h[2][HID_];
    h[0][j] = 0.f;

    float* xwb = xw + (size_t)b * S_ * HID_;
    float xnext = xwb[j];
    __syncthreads();

    for (int t = 0; t < S_; ++t) {
        const float x = xnext;
        xnext = (t < S_ - 1) ? xwb[(size_t)(t + 1) * HID_ + j] : 0.f;

        const float4* h4 = (const float4*)(h[t & 1]);
        float a0 = x, a1 = 0.f, a2 = 0.f, a3 = 0.f;
        float a4 = 0.f, a5 = 0.f, a6 = 0.f, a7 = 0.f;
#pragma unroll
        for (int q = 0; q < 16; ++q) {
            float4 u = h4[2 * q];
            float4 v = h4[2 * q + 1];
            a0 += u.x * w[8 * q + 0];
            a1 += u.y * w[8 * q + 1];
            a2 += u.z * w[8 * q + 2];
            a3 += u.w * w[8 * q + 3];
            a4 += v.x * w[8 * q + 4];
            a5 += v.y * w[8 * q + 5];
            a6 += v.z * w[8 * q + 6];
            a7 += v.w * w[8 * q + 7];
        }
        const float acc = ((a0 + a1) + (a2 + a3)) + ((a4 + a5) + (a6 + a7));
        const float hn = tanhf(acc);

        h[(t + 1) & 1][j] = hn;
        xwb[(size_t)t * HID_ + j] = hn;
        __syncthreads();
    }
}

// ---------------------------------------------------------------------------
// K3: logits = hs @ W_out + b_out, log-softmax, per-block NLL partial sums.
// 1024 blocks x 128 threads; each thread owns one position.
// ---------------------------------------------------------------------------
__global__ __launch_bounds__(128, 2) void head_kernel(
    const float* __restrict__ hs,
    const float* __restrict__ W_out,
    const float* __restrict__ b_out,
    const int* __restrict__ labels,
    float* __restrict__ logits,
    float* __restrict__ partial)
{
    __shared__ float tile[128][129];   // +1 pad: conflict-free row reads
    __shared__ float wT[NL_][HID_];
    __shared__ float red[2];

    const int j = threadIdx.x;
    const int tpos = blockIdx.x * 128;

#pragma unroll
    for (int l = 0; l < NL_; ++l) wT[l][j] = W_out[j * NL_ + l];

    for (int p = 0; p < 128; ++p)
        tile[p][j] = hs[(size_t)(tpos + p) * HID_ + j];
    __syncthreads();

    float acc[NL_];
#pragma unroll
    for (int l = 0; l < NL_; ++l) acc[l] = b_out[l];

#pragma unroll 4
    for (int e = 0; e < HID_; ++e) {
        const float hv = tile[j][e];
#pragma unroll
        for (int l = 0; l < NL_; ++l) acc[l] += hv * wT[l][e];
    }

    // log-softmax over 9 + NLL
    float m = acc[0];
#pragma unroll
    for (int l = 1; l < NL_; ++l) m = fmaxf(m, acc[l]);
    float s = 0.f;
#pragma unroll
    for (int l = 0; l < NL_; ++l) s += __expf(acc[l] - m);
    const float logZ = m + __logf(s);

    const int lab = labels[tpos + j];
    float accl = 0.f;
#pragma unroll
    for (int l = 0; l < NL_; ++l) accl = (l == lab) ? acc[l] : accl;
    float v = logZ - accl;   // -log p[label]

    // block reduction of v
#pragma unroll
    for (int off = 32; off > 0; off >>= 1) v += __shfl_down(v, off, 64);

    __syncthreads();   // done reading tile; reuse it for logits restage
    if ((j & 63) == 0) red[j >> 6] = v;

    float* lt = &tile[0][0];
#pragma unroll
    for (int l = 0; l < NL_; ++l) lt[j * NL_ + l] = acc[l];
    __syncthreads();

    if (j == 0) partial[blockIdx.x] = red[0] + red[1];
    for (int i = j; i < 128 * NL_; i += 128)
        logits[(size_t)tpos * NL_ + i] = lt[i];
}

// ---------------------------------------------------------------------------
// K4: reduce 1024 partials -> loss scalar at d_out[NPOS*NL_]
// ---------------------------------------------------------------------------
__global__ __launch_bounds__(256) void loss_kernel(
    const float* __restrict__ partial,
    float* __restrict__ out)
{
    __shared__ float red[4];
    const int j = threadIdx.x;
    float s = 0.f;
    for (int i = j; i < NBLK_HEAD; i += 256) s += partial[i];
#pragma unroll
    for (int off = 32; off > 0; off >>= 1) s += __shfl_down(s, off, 64);
    if ((j & 63) == 0) red[j >> 6] = s;
    __syncthreads();
    if (j == 0)
        out[(size_t)NPOS * NL_] =
            (red[0] + red[1] + red[2] + red[3]) * (1.0f / (float)NPOS);
}

// ---------------------------------------------------------------------------
extern "C" void kernel_launch(void* const* d_in, const int* in_sizes, int n_in,
                              void* d_out, int out_size, void* d_ws, size_t ws_size,
                              hipStream_t stream) {
    const int*   ids    = (const int*)d_in[0];
    // d_in[1] attention_mask, d_in[2] token_type_ids: unused by reference math
    const int*   labels = (const int*)d_in[3];
    const float* emb    = (const float*)d_in[4];
    const float* W_h    = (const float*)d_in[5];
    const float* b_h    = (const float*)d_in[6];
    const float* W_out  = (const float*)d_in[7];
    const float* b_out  = (const float*)d_in[8];
    float* out = (float*)d_out;

    float* xw      = (float*)d_ws;                       // NPOS*HID floats (64 MB)
    float* partial = xw + (size_t)NPOS * HID_;           // NBLK_HEAD floats

    xw_kernel  <<<NBLK_HEAD, 128, 0, stream>>>(ids, emb, W_h, b_h, xw);
    rnn_kernel <<<B_,        128, 0, stream>>>(W_h, xw);
    head_kernel<<<NBLK_HEAD, 128, 0, stream>>>(xw, W_out, b_out, labels, out, partial);
    loss_kernel<<<1,         256, 0, stream>>>(partial, out);
}

// Round 3
// 720.464 us; speedup vs baseline: 1.4655x; 1.4655x over previous
//
#include <hip/hip_runtime.h>
#include <hip/hip_bf16.h>
#include <math.h>

#define B_   128
#define S_   1024
#define EMB_ 128
#define HID_ 128
#define NL_  9
#define NPOS (B_ * S_)          // 131072
#define NBLK_HEAD (NPOS / 128)  // 1024

typedef __bf16 bf16x8 __attribute__((ext_vector_type(8)));
typedef float  f32x4  __attribute__((ext_vector_type(4)));

// ---------------------------------------------------------------------------
// K1: xw[pos][j] = sum_e emb[ids[pos]][e] * W_h[e][j] + b_h[j]   (unchanged)
// ---------------------------------------------------------------------------
__global__ __launch_bounds__(128, 2) void xw_kernel(
    const int* __restrict__ ids,
    const float* __restrict__ emb,
    const float* __restrict__ W_h,
    const float* __restrict__ b_h,
    float* __restrict__ xw)
{
    const int j = threadIdx.x;
    float w[EMB_];
#pragma unroll
    for (int e = 0; e < EMB_; ++e) w[e] = W_h[e * HID_ + j];
    const float bj = b_h[j];

    __shared__ float rows[8][EMB_];
    const int base = blockIdx.x * 128;

    for (int p0 = 0; p0 < 128; p0 += 8) {
        __syncthreads();
#pragma unroll
        for (int r = 0; r < 8; ++r) {
            const int pos = base + p0 + r;
            rows[r][j] = emb[(size_t)ids[pos] * EMB_ + j];
        }
        __syncthreads();
#pragma unroll
        for (int r = 0; r < 8; ++r) {
            const int pos = base + p0 + r;
            const float4* h4 = (const float4*)rows[r];
            float a0 = bj, a1 = 0.f, a2 = 0.f, a3 = 0.f;
#pragma unroll
            for (int q = 0; q < EMB_ / 4; ++q) {
                float4 u = h4[q];
                a0 += u.x * w[4 * q + 0];
                a1 += u.y * w[4 * q + 1];
                a2 += u.z * w[4 * q + 2];
                a3 += u.w * w[4 * q + 3];
            }
            xw[(size_t)pos * HID_ + j] = (a0 + a1) + (a2 + a3);
        }
    }
}

// ---------------------------------------------------------------------------
// K2: MFMA-batched recurrence.
// 8 blocks x 256 threads; block handles 16 batch rows (M=16).
// Per step: C[16x128] = A(h_t, bf16)[16x128] @ B(Wh, bf16)[128x128], fp32 acc,
// + xw (fp32, prefetched 2 steps ahead), tanh, write back.
// Wave w owns N-columns [32w, 32w+32) -> 2 N-tiles x 4 K-tiles = 8 MFMAs.
// h double-buffered in LDS (A-fragment-friendly layout, +8 bf16 row pad).
// ---------------------------------------------------------------------------
#define LDSK 136   // 128 + 8 pad (keeps 16B alignment, breaks bank aliasing)

__device__ __forceinline__ float fast_tanh(float x) {
    // tanh(x) = 1 - 2/(2^(x*2*log2(e)) + 1); exact saturation at +-inf
    float e = __builtin_amdgcn_exp2f(x * 2.885390081777927f);  // v_exp_f32
    return 1.0f - 2.0f * __builtin_amdgcn_rcpf(e + 1.0f);
}

__global__ __launch_bounds__(256, 1) void rnn_mfma_kernel(
    const float* __restrict__ W_h,
    float* __restrict__ xw)   // in: xw, out: hidden states (in-place)
{
    const int wave = threadIdx.x >> 6;   // 0..3
    const int lane = threadIdx.x & 63;
    const int l    = lane & 15;          // tile col (n) / A-row (m)
    const int q    = lane >> 4;          // quad 0..3
    const int b0   = blockIdx.x * 16;

    // --- B fragments: Wh[k][n] ; n = (2*wave+nl)*16 + l, k = kt*32 + q*8 + j
    bf16x8 wfrag[4][2];
#pragma unroll
    for (int kt = 0; kt < 4; ++kt)
#pragma unroll
        for (int nl = 0; nl < 2; ++nl) {
            const int n = (wave * 2 + nl) * 16 + l;
            const int kb = kt * 32 + q * 8;
            bf16x8 f;
#pragma unroll
            for (int j = 0; j < 8; ++j)
                f[j] = (__bf16)W_h[(size_t)(EMB_ + kb + j) * HID_ + n];
            wfrag[kt][nl] = f;
        }

    // --- h double buffer in LDS
    __shared__ __align__(16) __bf16 hl[2][16 * LDSK];
    for (int i = threadIdx.x; i < 2 * 16 * LDSK; i += 256)
        (&hl[0][0])[i] = (__bf16)0.f;

    // --- xw pointers in C-fragment order: (nl, r) -> batch m = q*4+r, col n
    float* p[2][4];
#pragma unroll
    for (int nl = 0; nl < 2; ++nl)
#pragma unroll
        for (int r = 0; r < 4; ++r)
            p[nl][r] = xw + ((size_t)(b0 + q * 4 + r) * S_) * HID_
                          + (wave * 2 + nl) * 16 + l;

    // prefetch t=0 (xb0) and t=1 (xb1)
    float xb0[2][4], xb1[2][4];
#pragma unroll
    for (int nl = 0; nl < 2; ++nl)
#pragma unroll
        for (int r = 0; r < 4; ++r) {
            xb0[nl][r] = p[nl][r][0];
            xb1[nl][r] = p[nl][r][HID_];
        }

    __syncthreads();

#pragma unroll 1
    for (int t = 0; t < S_; t += 2) {
#pragma unroll
        for (int u = 0; u < 2; ++u) {          // u=0 -> t, u=1 -> t+1
            const __bf16* hsrc = hl[u];        // (t+u)&1 == u  (t even)
            __bf16*       hdst = hl[u ^ 1];

            // A fragments: A[m=l][k]
            bf16x8 afrag[4];
#pragma unroll
            for (int kt = 0; kt < 4; ++kt)
                afrag[kt] = *(const bf16x8*)&hsrc[l * LDSK + kt * 32 + q * 8];

            f32x4 acc0 = {0.f, 0.f, 0.f, 0.f};
            f32x4 acc1 = {0.f, 0.f, 0.f, 0.f};
#pragma unroll
            for (int kt = 0; kt < 4; ++kt) {
                acc0 = __builtin_amdgcn_mfma_f32_16x16x32_bf16(
                           afrag[kt], wfrag[kt][0], acc0, 0, 0, 0);
                acc1 = __builtin_amdgcn_mfma_f32_16x16x32_bf16(
                           afrag[kt], wfrag[kt][1], acc1, 0, 0, 0);
            }

            // epilogue: add xw, tanh, store hs (fp32), stage h_{t+1} (bf16)
#pragma unroll
            for (int nl = 0; nl < 2; ++nl) {
#pragma unroll
                for (int r = 0; r < 4; ++r) {
                    const float pre = (nl ? acc1[r] : acc0[r])
                                    + (u ? xb1[nl][r] : xb0[nl][r]);
                    const float hf = fast_tanh(pre);
                    // global hs write at position t+u
                    p[nl][r][(size_t)(t + u) * HID_] = hf;
                    // prefetch xw for step t+u+2 into the freed buffer
                    const float xf = p[nl][r][(size_t)(t + u + 2) * HID_];
                    if (u) xb1[nl][r] = xf; else xb0[nl][r] = xf;
                    // LDS write in A-layout: row m = q*4+r, col n
                    hdst[(q * 4 + r) * LDSK + (wave * 2 + nl) * 16 + l] =
                        (__bf16)hf;
                }
            }
            __syncthreads();   // h_{t+u+1} visible before next step's reads
        }
    }
    // NOTE: prefetch at t=1022/1023 reads 2 rows past xw's 64MB region; that
    // memory is the partial[] scratch (in-bounds of d_ws), values never used.
}

// ---------------------------------------------------------------------------
// K3: logits + log-softmax + per-block NLL partials   (unchanged)
// ---------------------------------------------------------------------------
__global__ __launch_bounds__(128, 2) void head_kernel(
    const float* __restrict__ hs,
    const float* __restrict__ W_out,
    const float* __restrict__ b_out,
    const int* __restrict__ labels,
    float* __restrict__ logits,
    float* __restrict__ partial)
{
    __shared__ float tile[128][129];
    __shared__ float wT[NL_][HID_];
    __shared__ float red[2];

    const int j = threadIdx.x;
    const int tpos = blockIdx.x * 128;

#pragma unroll
    for (int l = 0; l < NL_; ++l) wT[l][j] = W_out[j * NL_ + l];

    for (int p = 0; p < 128; ++p)
        tile[p][j] = hs[(size_t)(tpos + p) * HID_ + j];
    __syncthreads();

    float acc[NL_];
#pragma unroll
    for (int l = 0; l < NL_; ++l) acc[l] = b_out[l];

#pragma unroll 4
    for (int e = 0; e < HID_; ++e) {
        const float hv = tile[j][e];
#pragma unroll
        for (int l = 0; l < NL_; ++l) acc[l] += hv * wT[l][e];
    }

    float m = acc[0];
#pragma unroll
    for (int l = 1; l < NL_; ++l) m = fmaxf(m, acc[l]);
    float s = 0.f;
#pragma unroll
    for (int l = 0; l < NL_; ++l) s += __expf(acc[l] - m);
    const float logZ = m + __logf(s);

    const int lab = labels[tpos + j];
    float accl = 0.f;
#pragma unroll
    for (int l = 0; l < NL_; ++l) accl = (l == lab) ? acc[l] : accl;
    float v = logZ - accl;

#pragma unroll
    for (int off = 32; off > 0; off >>= 1) v += __shfl_down(v, off, 64);

    __syncthreads();
    if ((j & 63) == 0) red[j >> 6] = v;

    float* lt = &tile[0][0];
#pragma unroll
    for (int l = 0; l < NL_; ++l) lt[j * NL_ + l] = acc[l];
    __syncthreads();

    if (j == 0) partial[blockIdx.x] = red[0] + red[1];
    for (int i = j; i < 128 * NL_; i += 128)
        logits[(size_t)tpos * NL_ + i] = lt[i];
}

// ---------------------------------------------------------------------------
// K4: reduce partials -> loss scalar   (unchanged)
// ---------------------------------------------------------------------------
__global__ __launch_bounds__(256) void loss_kernel(
    const float* __restrict__ partial,
    float* __restrict__ out)
{
    __shared__ float red[4];
    const int j = threadIdx.x;
    float s = 0.f;
    for (int i = j; i < NBLK_HEAD; i += 256) s += partial[i];
#pragma unroll
    for (int off = 32; off > 0; off >>= 1) s += __shfl_down(s, off, 64);
    if ((j & 63) == 0) red[j >> 6] = s;
    __syncthreads();
    if (j == 0)
        out[(size_t)NPOS * NL_] =
            (red[0] + red[1] + red[2] + red[3]) * (1.0f / (float)NPOS);
}

// ---------------------------------------------------------------------------
extern "C" void kernel_launch(void* const* d_in, const int* in_sizes, int n_in,
                              void* d_out, int out_size, void* d_ws, size_t ws_size,
                              hipStream_t stream) {
    const int*   ids    = (const int*)d_in[0];
    const int*   labels = (const int*)d_in[3];
    const float* emb    = (const float*)d_in[4];
    const float* W_h    = (const float*)d_in[5];
    const float* b_h    = (const float*)d_in[6];
    const float* W_out  = (const float*)d_in[7];
    const float* b_out  = (const float*)d_in[8];
    float* out = (float*)d_out;

    float* xw      = (float*)d_ws;              // NPOS*HID floats (64 MB)
    float* partial = xw + (size_t)NPOS * HID_;  // NBLK_HEAD floats

    xw_kernel      <<<NBLK_HEAD, 128, 0, stream>>>(ids, emb, W_h, b_h, xw);
    rnn_mfma_kernel<<<B_ / 16,   256, 0, stream>>>(W_h, xw);
    head_kernel    <<<NBLK_HEAD, 128, 0, stream>>>(xw, W_out, b_out, labels, out, partial);
    loss_kernel    <<<1,         256, 0, stream>>>(partial, out);
}